// Round 1
// baseline (4477.683 us; speedup 1.0000x reference)
//
#include <hip/hip_runtime.h>

#define NN 100000
#define NE 1600000
#define NG 512

// ---------------- tiled f32 GEMM: C[M,N] = op(A[M,K]) @ B[K,N], N == BN ----------------
template<int BM, int BN, int BK, bool RELU_IN>
__global__ __launch_bounds__(256) void gemm_f32(const float* __restrict__ A,
                                                const float* __restrict__ B,
                                                float* __restrict__ C,
                                                int M, int K, int N) {
  constexpr int TC  = BN / 4;     // float4 column groups
  constexpr int TR  = 256 / TC;   // row groups
  constexpr int RPT = BM / TR;    // rows per thread
  __shared__ float As[BK * BM];   // transposed: As[k*BM + row]
  __shared__ float Bs[BK * BN];

  const int tid  = threadIdx.x;
  const int tcol = tid % TC;
  const int trow = tid / TC;
  const int blockRow = blockIdx.x * BM;

  float acc[RPT][4];
#pragma unroll
  for (int r = 0; r < RPT; ++r)
#pragma unroll
    for (int j = 0; j < 4; ++j) acc[r][j] = 0.f;

  for (int kk = 0; kk < K; kk += BK) {
    // stage A tile (transposed), zero-fill OOB rows
#pragma unroll
    for (int it = 0; it < (BM * BK) / (256 * 4); ++it) {
      int idx = tid + it * 256;          // float4 index in tile
      int row = idx / (BK / 4);
      int k4  = idx % (BK / 4);
      float4 v = make_float4(0.f, 0.f, 0.f, 0.f);
      int grow = blockRow + row;
      if (grow < M) {
        v = *reinterpret_cast<const float4*>(A + (size_t)grow * K + kk + k4 * 4);
        if (RELU_IN) {
          v.x = fmaxf(v.x, 0.f); v.y = fmaxf(v.y, 0.f);
          v.z = fmaxf(v.z, 0.f); v.w = fmaxf(v.w, 0.f);
        }
      }
      As[(k4 * 4 + 0) * BM + row] = v.x;
      As[(k4 * 4 + 1) * BM + row] = v.y;
      As[(k4 * 4 + 2) * BM + row] = v.z;
      As[(k4 * 4 + 3) * BM + row] = v.w;
    }
    // stage B tile (K,N always multiples of tile)
#pragma unroll
    for (int it = 0; it < (BK * BN) / (256 * 4); ++it) {
      int idx = tid + it * 256;
      int kr  = idx / (BN / 4);
      int c4  = idx % (BN / 4);
      *reinterpret_cast<float4*>(Bs + kr * BN + c4 * 4) =
          *reinterpret_cast<const float4*>(B + (size_t)(kk + kr) * N + c4 * 4);
    }
    __syncthreads();

#pragma unroll
    for (int k = 0; k < BK; ++k) {
      float4 b = *reinterpret_cast<const float4*>(Bs + k * BN + tcol * 4);
      float a[RPT];
#pragma unroll
      for (int r4 = 0; r4 < RPT / 4; ++r4) {
        float4 av = *reinterpret_cast<const float4*>(As + k * BM + trow * RPT + r4 * 4);
        a[r4 * 4 + 0] = av.x; a[r4 * 4 + 1] = av.y;
        a[r4 * 4 + 2] = av.z; a[r4 * 4 + 3] = av.w;
      }
#pragma unroll
      for (int r = 0; r < RPT; ++r) {
        acc[r][0] += a[r] * b.x;
        acc[r][1] += a[r] * b.y;
        acc[r][2] += a[r] * b.z;
        acc[r][3] += a[r] * b.w;
      }
    }
    __syncthreads();
  }

#pragma unroll
  for (int r = 0; r < RPT; ++r) {
    int grow = blockRow + trow * RPT + r;
    if (grow < M) {
      float4 o = make_float4(acc[r][0], acc[r][1], acc[r][2], acc[r][3]);
      *reinterpret_cast<float4*>(C + (size_t)grow * N + tcol * 4) = o;
    }
  }
}

// ---------------- degree histogram & rsqrt ----------------
__global__ void deg_kernel(const int* __restrict__ dst, float* __restrict__ degf, int E) {
  int e = blockIdx.x * blockDim.x + threadIdx.x;
  if (e < E) atomicAdd(&degf[dst[e]], 1.0f);
}

__global__ void dinv_kernel(float* __restrict__ d, int N) {
  int n = blockIdx.x * blockDim.x + threadIdx.x;
  if (n < N) d[n] = rsqrtf(d[n] + 1.0f);
}

// ---------------- agg init with self-loop + bias: agg = h*dinv^2 + b ----------------
template<int C4>
__global__ void init_self(const float4* __restrict__ h4, const float* __restrict__ dinv,
                          const float* __restrict__ bias, float4* __restrict__ agg, int N) {
  int gid = blockIdx.x * blockDim.x + threadIdx.x;
  int n = gid / C4, c = gid % C4;
  if (n >= N) return;
  float di = dinv[n];
  float s  = di * di;
  float4 v = h4[(size_t)n * C4 + c];
  float4 b = reinterpret_cast<const float4*>(bias)[c];
  float4 o;
  o.x = v.x * s + b.x; o.y = v.y * s + b.y;
  o.z = v.z * s + b.z; o.w = v.w * s + b.w;
  agg[(size_t)n * C4 + c] = o;
}

// ---------------- edge scatter-add: agg[dst] += h[src] * dinv[src]*dinv[dst] ----------------
template<int C4>
__global__ void edge_agg(const float4* __restrict__ h4, const float* __restrict__ dinv,
                         const int* __restrict__ src, const int* __restrict__ dst,
                         float* __restrict__ agg, int E) {
  int gid = blockIdx.x * blockDim.x + threadIdx.x;
  int e = gid / C4, c = gid % C4;
  if (e >= E) return;
  int s = src[e], d = dst[e];
  float nrm = dinv[s] * dinv[d];
  float4 v = h4[(size_t)s * C4 + c];
  float* o = agg + ((size_t)d * C4 + c) * 4;
  atomicAdd(o + 0, v.x * nrm);
  atomicAdd(o + 1, v.y * nrm);
  atomicAdd(o + 2, v.z * nrm);
  atomicAdd(o + 3, v.w * nrm);
}

// ---------------- mean-pool accumulate (F=64) ----------------
__global__ void pool_kernel(const float4* __restrict__ h4, const int* __restrict__ batch,
                            float* __restrict__ psum, float* __restrict__ pcnt, int N) {
  int gid = blockIdx.x * blockDim.x + threadIdx.x;
  int n = gid >> 4, c = gid & 15;
  if (n >= N) return;
  int g = batch[n];
  float4 v = h4[(size_t)n * 16 + c];
  float* o = psum + g * 64 + c * 4;
  atomicAdd(o + 0, v.x); atomicAdd(o + 1, v.y);
  atomicAdd(o + 2, v.z); atomicAdd(o + 3, v.w);
  if (c == 0) atomicAdd(&pcnt[g], 1.0f);
}

// ---------------- per-graph MLP: sigmoid(relu([emb,scal]@W3+b3)@W4+b4) ----------------
__global__ __launch_bounds__(128) void graph_mlp(const float* __restrict__ psum,
                                                 const float* __restrict__ pcnt,
                                                 const float* __restrict__ scalars,
                                                 const float* __restrict__ W3,
                                                 const float* __restrict__ b3,
                                                 const float* __restrict__ W4,
                                                 const float* __restrict__ b4,
                                                 float* __restrict__ out) {
  int g = blockIdx.x;
  int t = threadIdx.x; // 128
  __shared__ float comb[66];
  __shared__ float part[2];
  if (t < 64)       comb[t] = psum[g * 64 + t] / fmaxf(pcnt[g], 1.0f);
  else if (t < 66)  comb[t] = scalars[g * 2 + (t - 64)];
  __syncthreads();
  float h = b3[t];
#pragma unroll
  for (int k = 0; k < 66; ++k) h += comb[k] * W3[k * 128 + t];
  h = fmaxf(h, 0.f);
  float p = h * W4[t];
#pragma unroll
  for (int off = 32; off > 0; off >>= 1) p += __shfl_down(p, off);
  if ((t & 63) == 0) part[t >> 6] = p;
  __syncthreads();
  if (t == 0) {
    float s = part[0] + part[1] + b4[0];
    out[g] = 1.f / (1.f + expf(-s));
  }
}

extern "C" void kernel_launch(void* const* d_in, const int* in_sizes, int n_in,
                              void* d_out, int out_size, void* d_ws, size_t ws_size,
                              hipStream_t stream) {
  const float* x       = (const float*)d_in[0];
  const int*   ei      = (const int*)d_in[1];
  const int*   src     = ei;
  const int*   dstp    = ei + NE;
  const int*   batch   = (const int*)d_in[2];
  const float* scalars = (const float*)d_in[3];
  const float* W1 = (const float*)d_in[4];  const float* b1 = (const float*)d_in[5];
  const float* W2 = (const float*)d_in[6];  const float* b2 = (const float*)d_in[7];
  const float* W3 = (const float*)d_in[8];  const float* b3 = (const float*)d_in[9];
  const float* W4 = (const float*)d_in[10]; const float* b4 = (const float*)d_in[11];
  float* out = (float*)d_out;

  // workspace layout (floats)
  float* ws   = (float*)d_ws;
  float* hx   = ws;              // [100000,128] x@W1 ; reused as h2pre [100000,64]
  float* agg1 = ws + 12800000;   // [100000,128] conv1 out ; reused as conv2 out
  float* dinv = agg1 + 12800000; // [100000] degree -> rsqrt
  float* psum = dinv + 100000;   // [512,64]
  float* pcnt = psum + 512 * 64; // [512]

  // zero degree + pool accumulators (agg buffers are init-overwritten)
  hipMemsetAsync(dinv, 0, (size_t)(100000 + 512 * 64 + 512) * sizeof(float), stream);

  // conv1: hx = x @ W1
  gemm_f32<64, 128, 32, false><<<(NN + 63) / 64, 256, 0, stream>>>(x, W1, hx, NN, 256, 128);
  deg_kernel<<<(NE + 255) / 256, 256, 0, stream>>>(dstp, dinv, NE);
  dinv_kernel<<<(NN + 255) / 256, 256, 0, stream>>>(dinv, NN);
  init_self<32><<<(NN * 32) / 256, 256, 0, stream>>>((const float4*)hx, dinv, b1,
                                                     (float4*)agg1, NN);
  edge_agg<32><<<(NE / 256) * 32, 256, 0, stream>>>((const float4*)hx, dinv, src, dstp,
                                                    agg1, NE);
  // conv2: h2pre = relu(agg1) @ W2  (into hx region)
  gemm_f32<64, 64, 32, true><<<(NN + 63) / 64, 256, 0, stream>>>(agg1, W2, hx, NN, 128, 64);
  init_self<16><<<(NN * 16) / 256, 256, 0, stream>>>((const float4*)hx, dinv, b2,
                                                     (float4*)agg1, NN);
  edge_agg<16><<<(NE / 256) * 16, 256, 0, stream>>>((const float4*)hx, dinv, src, dstp,
                                                    agg1, NE);
  // mean pool + graph MLP
  pool_kernel<<<(NN * 16 + 255) / 256, 256, 0, stream>>>((const float4*)agg1, batch,
                                                         psum, pcnt, NN);
  graph_mlp<<<NG, 128, 0, stream>>>(psum, pcnt, scalars, W3, b3, W4, b4, out);
}

// Round 2
// 588.560 us; speedup vs baseline: 7.6079x; 7.6079x over previous
//
#include <hip/hip_runtime.h>

#define NN 100000
#define NE 1600000
#define NG 512
#define NB_SCAN 391   // ceil(NN/256)

// ---------------- tiled f32 GEMM: C[M,N] = op(A[M,K]) @ B[K,N] * dinv[row], N == BN ----------------
template<int BM, int BN, int BK, bool RELU_IN>
__global__ __launch_bounds__(256) void gemm_f32(const float* __restrict__ A,
                                                const float* __restrict__ B,
                                                const float* __restrict__ dinv,
                                                float* __restrict__ C,
                                                int M, int K, int N) {
  constexpr int TC  = BN / 4;     // float4 column groups
  constexpr int TR  = 256 / TC;   // row groups
  constexpr int RPT = BM / TR;    // rows per thread
  __shared__ float As[BK * BM];   // transposed: As[k*BM + row]
  __shared__ float Bs[BK * BN];

  const int tid  = threadIdx.x;
  const int tcol = tid % TC;
  const int trow = tid / TC;
  const int blockRow = blockIdx.x * BM;

  float acc[RPT][4];
#pragma unroll
  for (int r = 0; r < RPT; ++r)
#pragma unroll
    for (int j = 0; j < 4; ++j) acc[r][j] = 0.f;

  for (int kk = 0; kk < K; kk += BK) {
#pragma unroll
    for (int it = 0; it < (BM * BK) / (256 * 4); ++it) {
      int idx = tid + it * 256;          // float4 index in tile
      int row = idx / (BK / 4);
      int k4  = idx % (BK / 4);
      float4 v = make_float4(0.f, 0.f, 0.f, 0.f);
      int grow = blockRow + row;
      if (grow < M) {
        v = *reinterpret_cast<const float4*>(A + (size_t)grow * K + kk + k4 * 4);
        if (RELU_IN) {
          v.x = fmaxf(v.x, 0.f); v.y = fmaxf(v.y, 0.f);
          v.z = fmaxf(v.z, 0.f); v.w = fmaxf(v.w, 0.f);
        }
      }
      As[(k4 * 4 + 0) * BM + row] = v.x;
      As[(k4 * 4 + 1) * BM + row] = v.y;
      As[(k4 * 4 + 2) * BM + row] = v.z;
      As[(k4 * 4 + 3) * BM + row] = v.w;
    }
#pragma unroll
    for (int it = 0; it < (BK * BN) / (256 * 4); ++it) {
      int idx = tid + it * 256;
      int kr  = idx / (BN / 4);
      int c4  = idx % (BN / 4);
      *reinterpret_cast<float4*>(Bs + kr * BN + c4 * 4) =
          *reinterpret_cast<const float4*>(B + (size_t)(kk + kr) * N + c4 * 4);
    }
    __syncthreads();

#pragma unroll
    for (int k = 0; k < BK; ++k) {
      float4 b = *reinterpret_cast<const float4*>(Bs + k * BN + tcol * 4);
      float a[RPT];
#pragma unroll
      for (int r4 = 0; r4 < RPT / 4; ++r4) {
        float4 av = *reinterpret_cast<const float4*>(As + k * BM + trow * RPT + r4 * 4);
        a[r4 * 4 + 0] = av.x; a[r4 * 4 + 1] = av.y;
        a[r4 * 4 + 2] = av.z; a[r4 * 4 + 3] = av.w;
      }
#pragma unroll
      for (int r = 0; r < RPT; ++r) {
        acc[r][0] += a[r] * b.x;
        acc[r][1] += a[r] * b.y;
        acc[r][2] += a[r] * b.z;
        acc[r][3] += a[r] * b.w;
      }
    }
    __syncthreads();
  }

#pragma unroll
  for (int r = 0; r < RPT; ++r) {
    int grow = blockRow + trow * RPT + r;
    if (grow < M) {
      float s = dinv[grow];
      float4 o = make_float4(acc[r][0] * s, acc[r][1] * s, acc[r][2] * s, acc[r][3] * s);
      *reinterpret_cast<float4*>(C + (size_t)grow * N + tcol * 4) = o;
    }
  }
}

// ---------------- CSR build ----------------
__global__ void deg_int(const int* __restrict__ dst, int* __restrict__ deg, int E) {
  int e = blockIdx.x * blockDim.x + threadIdx.x;
  if (e < E) atomicAdd(&deg[dst[e]], 1);
}

__global__ void dinv_from_deg(const int* __restrict__ deg, float* __restrict__ dinv, int N) {
  int n = blockIdx.x * blockDim.x + threadIdx.x;
  if (n < N) dinv[n] = rsqrtf((float)deg[n] + 1.0f);
}

// per-block exclusive scan of deg -> row_off (local), block totals -> bsum
__global__ void scan_block(const int* __restrict__ deg, int* __restrict__ row_off,
                           int* __restrict__ bsum, int N) {
  __shared__ int s[256];
  int t = threadIdx.x;
  int i = blockIdx.x * 256 + t;
  int v = (i < N) ? deg[i] : 0;
  s[t] = v;
  __syncthreads();
  for (int off = 1; off < 256; off <<= 1) {
    int add = (t >= off) ? s[t - off] : 0;
    __syncthreads();
    s[t] += add;
    __syncthreads();
  }
  if (i < N) row_off[i] = s[t] - v;  // exclusive
  if (t == 255) bsum[blockIdx.x] = s[255];
}

// single-block exclusive scan of block sums
__global__ void scan_bsum(int* __restrict__ bsum, int NB) {
  __shared__ int s[512];
  int t = threadIdx.x;
  int v = (t < NB) ? bsum[t] : 0;
  s[t] = v;
  __syncthreads();
  for (int off = 1; off < 512; off <<= 1) {
    int add = (t >= off) ? s[t - off] : 0;
    __syncthreads();
    s[t] += add;
    __syncthreads();
  }
  if (t < NB) bsum[t] = s[t] - v;  // exclusive
}

__global__ void scan_final(int* __restrict__ row_off, int* __restrict__ cursor,
                           const int* __restrict__ bsum, int N, int E) {
  int i = blockIdx.x * 256 + threadIdx.x;
  if (i < N) {
    int r = row_off[i] + bsum[blockIdx.x];
    row_off[i] = r;
    cursor[i]  = r;
  }
  if (i == 0) row_off[N] = E;
}

__global__ void scatter_csr(const int* __restrict__ src, const int* __restrict__ dst,
                            int* __restrict__ cursor, int* __restrict__ csr, int E) {
  int e = blockIdx.x * blockDim.x + threadIdx.x;
  if (e < E) {
    int p = atomicAdd(&cursor[dst[e]], 1);
    csr[p] = src[e];
  }
}

// ---------------- CSR gather-reduce: out[n] = dinv[n]*(sum_src hs[src] + hs[n]) + b ----------------
// one wave (64 lanes) per node, F=128 -> float2 per lane
__global__ __launch_bounds__(256) void agg_csr_f128(const float2* __restrict__ hs,
                                                    const float* __restrict__ dinv,
                                                    const float* __restrict__ bias,
                                                    const int* __restrict__ row_off,
                                                    const int* __restrict__ csr,
                                                    float2* __restrict__ out, int N) {
  int node = blockIdx.x * 4 + (threadIdx.x >> 6);
  if (node >= N) return;
  int lane = threadIdx.x & 63;
  int beg = row_off[node], end = row_off[node + 1];
  float2 acc = hs[(size_t)node * 64 + lane];  // self term (already *dinv[n])
  int j = beg;
  for (; j + 4 <= end; j += 4) {
    int s0 = csr[j], s1 = csr[j + 1], s2 = csr[j + 2], s3 = csr[j + 3];
    float2 v0 = hs[(size_t)s0 * 64 + lane];
    float2 v1 = hs[(size_t)s1 * 64 + lane];
    float2 v2 = hs[(size_t)s2 * 64 + lane];
    float2 v3 = hs[(size_t)s3 * 64 + lane];
    acc.x += v0.x + v1.x + v2.x + v3.x;
    acc.y += v0.y + v1.y + v2.y + v3.y;
  }
  for (; j < end; ++j) {
    int s = csr[j];
    float2 v = hs[(size_t)s * 64 + lane];
    acc.x += v.x; acc.y += v.y;
  }
  float d = dinv[node];
  float2 b = reinterpret_cast<const float2*>(bias)[lane];
  float2 o;
  o.x = fmaf(acc.x, d, b.x);
  o.y = fmaf(acc.y, d, b.y);
  out[(size_t)node * 64 + lane] = o;
}

// F=64 -> one float per lane
__global__ __launch_bounds__(256) void agg_csr_f64(const float* __restrict__ hs,
                                                   const float* __restrict__ dinv,
                                                   const float* __restrict__ bias,
                                                   const int* __restrict__ row_off,
                                                   const int* __restrict__ csr,
                                                   float* __restrict__ out, int N) {
  int node = blockIdx.x * 4 + (threadIdx.x >> 6);
  if (node >= N) return;
  int lane = threadIdx.x & 63;
  int beg = row_off[node], end = row_off[node + 1];
  float acc = hs[(size_t)node * 64 + lane];
  int j = beg;
  for (; j + 4 <= end; j += 4) {
    int s0 = csr[j], s1 = csr[j + 1], s2 = csr[j + 2], s3 = csr[j + 3];
    acc += hs[(size_t)s0 * 64 + lane] + hs[(size_t)s1 * 64 + lane] +
           hs[(size_t)s2 * 64 + lane] + hs[(size_t)s3 * 64 + lane];
  }
  for (; j < end; ++j) acc += hs[(size_t)csr[j] * 64 + lane];
  out[(size_t)node * 64 + lane] = fmaf(acc, dinv[node], bias[lane]);
}

// ---------------- per-graph mean pool (batch sorted) -> emb66 = [mean(h), scalars] ----------------
__global__ __launch_bounds__(64) void pool_graph(const float* __restrict__ h,
                                                 const int* __restrict__ batch,
                                                 const float* __restrict__ scalars,
                                                 float* __restrict__ emb66, int N) {
  int g = blockIdx.x;
  int t = threadIdx.x;  // 64
  __shared__ int range[2];
  if (t < 2) {
    int target = g + t;
    int lo = 0, hi = N;
    while (lo < hi) { int mid = (lo + hi) >> 1; if (batch[mid] < target) lo = mid + 1; else hi = mid; }
    range[t] = lo;
  }
  __syncthreads();
  int beg = range[0], end = range[1];
  float s = 0.f;
  for (int i = beg; i < end; ++i) s += h[(size_t)i * 64 + t];
  float cnt = (float)(end - beg);
  emb66[g * 66 + t] = s / fmaxf(cnt, 1.f);
  if (t < 2) emb66[g * 66 + 64 + t] = scalars[g * 2 + t];
}

// ---------------- per-graph MLP: sigmoid(relu(comb@W3+b3)@W4+b4) ----------------
__global__ __launch_bounds__(128) void graph_mlp(const float* __restrict__ emb66,
                                                 const float* __restrict__ W3,
                                                 const float* __restrict__ b3,
                                                 const float* __restrict__ W4,
                                                 const float* __restrict__ b4,
                                                 float* __restrict__ out) {
  int g = blockIdx.x;
  int t = threadIdx.x;  // 128
  __shared__ float comb[66];
  __shared__ float part[2];
  if (t < 66) comb[t] = emb66[g * 66 + t];
  __syncthreads();
  float h = b3[t];
#pragma unroll
  for (int k = 0; k < 66; ++k) h += comb[k] * W3[k * 128 + t];
  h = fmaxf(h, 0.f);
  float p = h * W4[t];
#pragma unroll
  for (int off = 32; off > 0; off >>= 1) p += __shfl_down(p, off);
  if ((t & 63) == 0) part[t >> 6] = p;
  __syncthreads();
  if (t == 0) {
    float s = part[0] + part[1] + b4[0];
    out[g] = 1.f / (1.f + expf(-s));
  }
}

extern "C" void kernel_launch(void* const* d_in, const int* in_sizes, int n_in,
                              void* d_out, int out_size, void* d_ws, size_t ws_size,
                              hipStream_t stream) {
  const float* x       = (const float*)d_in[0];
  const int*   ei      = (const int*)d_in[1];
  const int*   src     = ei;
  const int*   dstp    = ei + NE;
  const int*   batch   = (const int*)d_in[2];
  const float* scalars = (const float*)d_in[3];
  const float* W1 = (const float*)d_in[4];  const float* b1 = (const float*)d_in[5];
  const float* W2 = (const float*)d_in[6];  const float* b2 = (const float*)d_in[7];
  const float* W3 = (const float*)d_in[8];  const float* b3 = (const float*)d_in[9];
  const float* W4 = (const float*)d_in[10]; const float* b4 = (const float*)d_in[11];
  float* out = (float*)d_out;

  // workspace layout (32-bit words)
  float* ws      = (float*)d_ws;
  float* hs1     = ws;                   // [100000,128] (x@W1)*dinv ; later hs2 [100000,64]
  float* agg1    = ws + 12800000;        // [100000,128] conv1 out   ; later agg2 [100000,64]
  float* dinv    = agg1 + 12800000;      // [100000]
  int*   deg     = (int*)(dinv + NN);    // [100000]
  int*   row_off = deg + NN;             // [100001]
  int*   cursor  = row_off + NN + 1;     // [100000]
  int*   bsum    = cursor + NN;          // [512]
  int*   csr     = bsum + 512;           // [1600000]
  float* emb66   = (float*)(csr + NE);   // [512,66]

  hipMemsetAsync(deg, 0, (size_t)NN * sizeof(int), stream);

  // CSR build + norms
  deg_int<<<(NE + 255) / 256, 256, 0, stream>>>(dstp, deg, NE);
  dinv_from_deg<<<NB_SCAN, 256, 0, stream>>>(deg, dinv, NN);
  scan_block<<<NB_SCAN, 256, 0, stream>>>(deg, row_off, bsum, NN);
  scan_bsum<<<1, 512, 0, stream>>>(bsum, NB_SCAN);
  scan_final<<<NB_SCAN, 256, 0, stream>>>(row_off, cursor, bsum, NN, NE);
  scatter_csr<<<(NE + 255) / 256, 256, 0, stream>>>(src, dstp, cursor, csr, NE);

  // conv1: hs1 = (x @ W1) * dinv ; agg1 = dinv*(gather-sum + self) + b1
  gemm_f32<64, 128, 32, false><<<(NN + 63) / 64, 256, 0, stream>>>(x, W1, dinv, hs1, NN, 256, 128);
  agg_csr_f128<<<(NN + 3) / 4, 256, 0, stream>>>((const float2*)hs1, dinv, b1, row_off, csr,
                                                 (float2*)agg1, NN);
  // conv2: hs2 = (relu(agg1) @ W2) * dinv ; agg2 = dinv*(gather-sum + self) + b2
  float* hs2  = hs1;   // reuse
  float* agg2 = agg1;  // reuse
  gemm_f32<64, 64, 32, true><<<(NN + 63) / 64, 256, 0, stream>>>(agg1, W2, dinv, hs2, NN, 128, 64);
  agg_csr_f64<<<(NN + 3) / 4, 256, 0, stream>>>(hs2, dinv, b2, row_off, csr, agg2, NN);

  // pool + MLP
  pool_graph<<<NG, 64, 0, stream>>>(agg2, batch, scalars, emb66, NN);
  graph_mlp<<<NG, 128, 0, stream>>>(emb66, W3, b3, W4, b4, out);
}

// Round 3
// 434.203 us; speedup vs baseline: 10.3124x; 1.3555x over previous
//
#include <hip/hip_runtime.h>

#define NN 100000
#define NE 1600000
#define NG 512
#define NB_SCAN 391   // ceil(NN/256)
#define NPART 8
#define NCHUNK 128

typedef unsigned int uint;

// ---- bf16 pack/unpack helpers (round-to-nearest-even) ----
__device__ inline uint f2bf2(float a, float b) {
  uint ua = __float_as_uint(a), ub = __float_as_uint(b);
  ua += 0x7fff + ((ua >> 16) & 1);
  ub += 0x7fff + ((ub >> 16) & 1);
  return (ua >> 16) | (ub & 0xffff0000u);
}
__device__ inline float2 bf2f(uint v) {
  float2 r;
  r.x = __uint_as_float(v << 16);
  r.y = __uint_as_float(v & 0xffff0000u);
  return r;
}

// ---------------- tiled f32 GEMM: C = op(A[M,K]) @ B[K,N] * dinv[row], N == BN ----------------
// OUT_BF16: C is [M,N] bf16 (packed pairs), else f32.
template<int BM, int BN, int BK, bool RELU_IN, bool OUT_BF16>
__global__ __launch_bounds__(256) void gemm_f32(const float* __restrict__ A,
                                                const float* __restrict__ B,
                                                const float* __restrict__ dinv,
                                                void* __restrict__ Cv,
                                                int M, int K, int N) {
  constexpr int TC  = BN / 4;
  constexpr int TR  = 256 / TC;
  constexpr int RPT = BM / TR;
  __shared__ float As[BK * BM];   // transposed: As[k*BM + row]
  __shared__ float Bs[BK * BN];

  const int tid  = threadIdx.x;
  const int tcol = tid % TC;
  const int trow = tid / TC;
  const int blockRow = blockIdx.x * BM;

  float acc[RPT][4];
#pragma unroll
  for (int r = 0; r < RPT; ++r)
#pragma unroll
    for (int j = 0; j < 4; ++j) acc[r][j] = 0.f;

  for (int kk = 0; kk < K; kk += BK) {
#pragma unroll
    for (int it = 0; it < (BM * BK) / (256 * 4); ++it) {
      int idx = tid + it * 256;
      int row = idx / (BK / 4);
      int k4  = idx % (BK / 4);
      float4 v = make_float4(0.f, 0.f, 0.f, 0.f);
      int grow = blockRow + row;
      if (grow < M) {
        v = *reinterpret_cast<const float4*>(A + (size_t)grow * K + kk + k4 * 4);
        if (RELU_IN) {
          v.x = fmaxf(v.x, 0.f); v.y = fmaxf(v.y, 0.f);
          v.z = fmaxf(v.z, 0.f); v.w = fmaxf(v.w, 0.f);
        }
      }
      As[(k4 * 4 + 0) * BM + row] = v.x;
      As[(k4 * 4 + 1) * BM + row] = v.y;
      As[(k4 * 4 + 2) * BM + row] = v.z;
      As[(k4 * 4 + 3) * BM + row] = v.w;
    }
#pragma unroll
    for (int it = 0; it < (BK * BN) / (256 * 4); ++it) {
      int idx = tid + it * 256;
      int kr  = idx / (BN / 4);
      int c4  = idx % (BN / 4);
      *reinterpret_cast<float4*>(Bs + kr * BN + c4 * 4) =
          *reinterpret_cast<const float4*>(B + (size_t)(kk + kr) * N + c4 * 4);
    }
    __syncthreads();

#pragma unroll
    for (int k = 0; k < BK; ++k) {
      float4 b = *reinterpret_cast<const float4*>(Bs + k * BN + tcol * 4);
      float a[RPT];
#pragma unroll
      for (int r4 = 0; r4 < RPT / 4; ++r4) {
        float4 av = *reinterpret_cast<const float4*>(As + k * BM + trow * RPT + r4 * 4);
        a[r4 * 4 + 0] = av.x; a[r4 * 4 + 1] = av.y;
        a[r4 * 4 + 2] = av.z; a[r4 * 4 + 3] = av.w;
      }
#pragma unroll
      for (int r = 0; r < RPT; ++r) {
        acc[r][0] += a[r] * b.x;
        acc[r][1] += a[r] * b.y;
        acc[r][2] += a[r] * b.z;
        acc[r][3] += a[r] * b.w;
      }
    }
    __syncthreads();
  }

#pragma unroll
  for (int r = 0; r < RPT; ++r) {
    int grow = blockRow + trow * RPT + r;
    if (grow < M) {
      float s = dinv[grow];
      if (OUT_BF16) {
        unsigned short* Cb = (unsigned short*)Cv;
        uint2 o;
        o.x = f2bf2(acc[r][0] * s, acc[r][1] * s);
        o.y = f2bf2(acc[r][2] * s, acc[r][3] * s);
        *reinterpret_cast<uint2*>(Cb + (size_t)grow * N + tcol * 4) = o;
      } else {
        float* C = (float*)Cv;
        float4 o = make_float4(acc[r][0] * s, acc[r][1] * s, acc[r][2] * s, acc[r][3] * s);
        *reinterpret_cast<float4*>(C + (size_t)grow * N + tcol * 4) = o;
      }
    }
  }
}

// ---------------- CSR build ----------------
__global__ void deg_int(const int* __restrict__ dst, int* __restrict__ deg, int E) {
  int e = blockIdx.x * blockDim.x + threadIdx.x;
  if (e < E) atomicAdd(&deg[dst[e]], 1);
}

__global__ void dinv_from_deg(const int* __restrict__ deg, float* __restrict__ dinv, int N) {
  int n = blockIdx.x * blockDim.x + threadIdx.x;
  if (n < N) dinv[n] = rsqrtf((float)deg[n] + 1.0f);
}

__global__ void scan_block(const int* __restrict__ deg, int* __restrict__ row_off,
                           int* __restrict__ bsum, int N) {
  __shared__ int s[256];
  int t = threadIdx.x;
  int i = blockIdx.x * 256 + t;
  int v = (i < N) ? deg[i] : 0;
  s[t] = v;
  __syncthreads();
  for (int off = 1; off < 256; off <<= 1) {
    int add = (t >= off) ? s[t - off] : 0;
    __syncthreads();
    s[t] += add;
    __syncthreads();
  }
  if (i < N) row_off[i] = s[t] - v;
  if (t == 255) bsum[blockIdx.x] = s[255];
}

__global__ void scan_bsum(int* __restrict__ bsum, int NB) {
  __shared__ int s[512];
  int t = threadIdx.x;
  int v = (t < NB) ? bsum[t] : 0;
  s[t] = v;
  __syncthreads();
  for (int off = 1; off < 512; off <<= 1) {
    int add = (t >= off) ? s[t - off] : 0;
    __syncthreads();
    s[t] += add;
    __syncthreads();
  }
  if (t < NB) bsum[t] = s[t] - v;
}

__global__ void scan_final(int* __restrict__ row_off, int* __restrict__ cursor,
                           const int* __restrict__ bsum, int N, int E) {
  int i = blockIdx.x * 256 + threadIdx.x;
  if (i < N) {
    int r = row_off[i] + bsum[blockIdx.x];
    row_off[i] = r;
    cursor[i]  = r;
  }
  if (i == 0) row_off[N] = E;
}

// XCD-partitioned scatter: part p (= blockIdx%8 -> XCD p) owns dst range
// [p*NN/8,(p+1)*NN/8); its csr writes stay in one L2 slice -> coalesced eviction.
__global__ __launch_bounds__(256) void scatter_csr_part(const int* __restrict__ src,
                                                        const int* __restrict__ dst,
                                                        int* __restrict__ cursor,
                                                        int* __restrict__ csr, int E) {
  int part  = blockIdx.x & (NPART - 1);
  int chunk = blockIdx.x / NPART;
  int per   = E / NCHUNK;
  int beg   = chunk * per, end = beg + per;
  int lo = part * (NN / NPART), hi = lo + (NN / NPART);
  for (int e = beg + threadIdx.x; e < end; e += 256) {
    int d = dst[e];
    if (d >= lo && d < hi) {
      int p = atomicAdd(&cursor[d], 1);
      csr[p] = src[e];
    }
  }
}

// ---------------- CSR gather-reduce from bf16 hs ----------------
// F=128: one wave per node, lane holds cols (2l, 2l+1) as packed bf16 pair
__global__ __launch_bounds__(256) void agg_csr_f128(const uint* __restrict__ hs,
                                                    const float* __restrict__ dinv,
                                                    const float* __restrict__ bias,
                                                    const int* __restrict__ row_off,
                                                    const int* __restrict__ csr,
                                                    float2* __restrict__ out, int N) {
  int node = blockIdx.x * 4 + (threadIdx.x >> 6);
  if (node >= N) return;
  int lane = threadIdx.x & 63;
  int beg = row_off[node], end = row_off[node + 1];
  float2 acc = bf2f(hs[(size_t)node * 64 + lane]);  // self term
  int j = beg;
  for (; j + 4 <= end; j += 4) {
    int s0 = csr[j], s1 = csr[j + 1], s2 = csr[j + 2], s3 = csr[j + 3];
    float2 v0 = bf2f(hs[(size_t)s0 * 64 + lane]);
    float2 v1 = bf2f(hs[(size_t)s1 * 64 + lane]);
    float2 v2 = bf2f(hs[(size_t)s2 * 64 + lane]);
    float2 v3 = bf2f(hs[(size_t)s3 * 64 + lane]);
    acc.x += (v0.x + v1.x) + (v2.x + v3.x);
    acc.y += (v0.y + v1.y) + (v2.y + v3.y);
  }
  for (; j < end; ++j) {
    float2 v = bf2f(hs[(size_t)csr[j] * 64 + lane]);
    acc.x += v.x; acc.y += v.y;
  }
  float d = dinv[node];
  float2 b = reinterpret_cast<const float2*>(bias)[lane];
  float2 o;
  o.x = fmaf(acc.x, d, b.x);
  o.y = fmaf(acc.y, d, b.y);
  out[(size_t)node * 64 + lane] = o;
}

// F=64: two nodes per wave (32 lanes each), lane holds packed col pair
__global__ __launch_bounds__(256) void agg_csr_f64(const uint* __restrict__ hs,
                                                   const float* __restrict__ dinv,
                                                   const float* __restrict__ bias,
                                                   const int* __restrict__ row_off,
                                                   const int* __restrict__ csr,
                                                   float2* __restrict__ out, int N) {
  int node = blockIdx.x * 8 + (threadIdx.x >> 5);
  if (node >= N) return;
  int lane2 = threadIdx.x & 31;
  int beg = row_off[node], end = row_off[node + 1];
  float2 acc = bf2f(hs[(size_t)node * 32 + lane2]);
  int j = beg;
  for (; j + 4 <= end; j += 4) {
    int s0 = csr[j], s1 = csr[j + 1], s2 = csr[j + 2], s3 = csr[j + 3];
    float2 v0 = bf2f(hs[(size_t)s0 * 32 + lane2]);
    float2 v1 = bf2f(hs[(size_t)s1 * 32 + lane2]);
    float2 v2 = bf2f(hs[(size_t)s2 * 32 + lane2]);
    float2 v3 = bf2f(hs[(size_t)s3 * 32 + lane2]);
    acc.x += (v0.x + v1.x) + (v2.x + v3.x);
    acc.y += (v0.y + v1.y) + (v2.y + v3.y);
  }
  for (; j < end; ++j) {
    float2 v = bf2f(hs[(size_t)csr[j] * 32 + lane2]);
    acc.x += v.x; acc.y += v.y;
  }
  float d = dinv[node];
  float2 b = reinterpret_cast<const float2*>(bias)[lane2];
  float2 o;
  o.x = fmaf(acc.x, d, b.x);
  o.y = fmaf(acc.y, d, b.y);
  out[(size_t)node * 32 + lane2] = o;
}

// ---------------- per-graph mean pool (batch sorted) ----------------
__global__ __launch_bounds__(256) void pool_graph(const float* __restrict__ h,
                                                  const int* __restrict__ batch,
                                                  const float* __restrict__ scalars,
                                                  float* __restrict__ emb66, int N) {
  int g = blockIdx.x;
  int t = threadIdx.x;  // 256
  int col = t & 63, rr = t >> 6;
  __shared__ int range[2];
  __shared__ float part[4][64];
  if (t < 2) {
    int target = g + t;
    int lo = 0, hi = N;
    while (lo < hi) { int mid = (lo + hi) >> 1; if (batch[mid] < target) lo = mid + 1; else hi = mid; }
    range[t] = lo;
  }
  __syncthreads();
  int beg = range[0], end = range[1];
  float s = 0.f;
  for (int i = beg + rr; i < end; i += 4) s += h[(size_t)i * 64 + col];
  part[rr][col] = s;
  __syncthreads();
  if (rr == 0) {
    float tot = (part[0][col] + part[1][col]) + (part[2][col] + part[3][col]);
    emb66[g * 66 + col] = tot / fmaxf((float)(end - beg), 1.f);
  } else if (t >= 64 && t < 66) {
    emb66[g * 66 + t] = scalars[g * 2 + (t - 64)];
  }
}

// ---------------- per-graph MLP ----------------
__global__ __launch_bounds__(128) void graph_mlp(const float* __restrict__ emb66,
                                                 const float* __restrict__ W3,
                                                 const float* __restrict__ b3,
                                                 const float* __restrict__ W4,
                                                 const float* __restrict__ b4,
                                                 float* __restrict__ out) {
  int g = blockIdx.x;
  int t = threadIdx.x;  // 128
  __shared__ float comb[66];
  __shared__ float part[2];
  if (t < 66) comb[t] = emb66[g * 66 + t];
  __syncthreads();
  float h = b3[t];
#pragma unroll
  for (int k = 0; k < 66; ++k) h += comb[k] * W3[k * 128 + t];
  h = fmaxf(h, 0.f);
  float p = h * W4[t];
#pragma unroll
  for (int off = 32; off > 0; off >>= 1) p += __shfl_down(p, off);
  if ((t & 63) == 0) part[t >> 6] = p;
  __syncthreads();
  if (t == 0) {
    float s = part[0] + part[1] + b4[0];
    out[g] = 1.f / (1.f + expf(-s));
  }
}

extern "C" void kernel_launch(void* const* d_in, const int* in_sizes, int n_in,
                              void* d_out, int out_size, void* d_ws, size_t ws_size,
                              hipStream_t stream) {
  const float* x       = (const float*)d_in[0];
  const int*   ei      = (const int*)d_in[1];
  const int*   src     = ei;
  const int*   dstp    = ei + NE;
  const int*   batch   = (const int*)d_in[2];
  const float* scalars = (const float*)d_in[3];
  const float* W1 = (const float*)d_in[4];  const float* b1 = (const float*)d_in[5];
  const float* W2 = (const float*)d_in[6];  const float* b2 = (const float*)d_in[7];
  const float* W3 = (const float*)d_in[8];  const float* b3 = (const float*)d_in[9];
  const float* W4 = (const float*)d_in[10]; const float* b4 = (const float*)d_in[11];
  float* out = (float*)d_out;

  // workspace layout (32-bit words)
  float* ws      = (float*)d_ws;
  uint*  hsb     = (uint*)ws;            // [100000,64] packed bf16 pairs (F=128); reused F=64 as [100000,32]
  float* agg1    = ws + 6400000;         // [100000,128] f32 ; reused as agg2 [100000,64]
  float* dinv    = agg1 + 12800000;      // [100000]
  int*   deg     = (int*)(dinv + NN);    // [100000]
  int*   row_off = deg + NN;             // [100001]
  int*   cursor  = row_off + NN + 1;     // [100000]
  int*   bsum    = cursor + NN;          // [512]
  int*   csr     = bsum + 512;           // [1600000]
  float* emb66   = (float*)(csr + NE);   // [512,66]

  hipMemsetAsync(deg, 0, (size_t)NN * sizeof(int), stream);

  // CSR build + norms
  deg_int<<<(NE + 255) / 256, 256, 0, stream>>>(dstp, deg, NE);
  dinv_from_deg<<<NB_SCAN, 256, 0, stream>>>(deg, dinv, NN);
  scan_block<<<NB_SCAN, 256, 0, stream>>>(deg, row_off, bsum, NN);
  scan_bsum<<<1, 512, 0, stream>>>(bsum, NB_SCAN);
  scan_final<<<NB_SCAN, 256, 0, stream>>>(row_off, cursor, bsum, NN, NE);
  scatter_csr_part<<<NPART * NCHUNK, 256, 0, stream>>>(src, dstp, cursor, csr, NE);

  // conv1: hsb = bf16((x @ W1) * dinv) ; agg1 = dinv*(gather-sum + self) + b1
  gemm_f32<64, 128, 32, false, true><<<(NN + 63) / 64, 256, 0, stream>>>(x, W1, dinv, hsb,
                                                                         NN, 256, 128);
  agg_csr_f128<<<(NN + 3) / 4, 256, 0, stream>>>(hsb, dinv, b1, row_off, csr,
                                                 (float2*)agg1, NN);
  // conv2: hsb = bf16((relu(agg1) @ W2) * dinv) ; agg2 = dinv*(gather-sum + self) + b2
  gemm_f32<64, 64, 32, true, true><<<(NN + 63) / 64, 256, 0, stream>>>(agg1, W2, dinv, hsb,
                                                                       NN, 128, 64);
  agg_csr_f64<<<(NN + 7) / 8, 256, 0, stream>>>(hsb, dinv, b2, row_off, csr,
                                                (float2*)agg1, NN);

  // pool + MLP
  pool_graph<<<NG, 256, 0, stream>>>(agg1, batch, scalars, emb66, NN);
  graph_mlp<<<NG, 128, 0, stream>>>(emb66, W3, b3, W4, b4, out);
}

// Round 4
// 354.329 us; speedup vs baseline: 12.6371x; 1.2254x over previous
//
#include <hip/hip_runtime.h>

#define NN 100000
#define NE 1600000
#define NG 512
#define NB_SCAN 391   // ceil(NN/256)
#define NPART 8
#define NCHUNK 128

typedef unsigned int uint;
typedef unsigned short ushort;
typedef __bf16 bf16x8 __attribute__((ext_vector_type(8)));
typedef float f32x4 __attribute__((ext_vector_type(4)));

// ---- bf16 pack helpers (round-to-nearest-even) ----
__device__ inline uint f2bf2(float a, float b) {
  uint ua = __float_as_uint(a), ub = __float_as_uint(b);
  ua += 0x7fff + ((ua >> 16) & 1);
  ub += 0x7fff + ((ub >> 16) & 1);
  return (ua >> 16) | (ub & 0xffff0000u);
}
__device__ inline ushort f2bf(float f) {
  uint u = __float_as_uint(f);
  u += 0x7fff + ((u >> 16) & 1);
  return (ushort)(u >> 16);
}
__device__ inline float2 bf2f(uint v) {
  float2 r;
  r.x = __uint_as_float(v << 16);
  r.y = __uint_as_float(v & 0xffff0000u);
  return r;
}
__device__ inline uint relu2(uint u) {
  uint lo = (u & 0x8000u) ? 0u : (u & 0xFFFFu);
  uint hi = (u & 0x80000000u) ? 0u : (u & 0xFFFF0000u);
  return lo | hi;
}

// ---------------- weight transpose + bf16 pack: Wt[n][k] = bf16(W[k][n]) ----------------
// one block per output row n; blockDim = K (<=256)
__global__ void transpose_w(const float* __restrict__ W, uint* __restrict__ Wt, int K, int N) {
  __shared__ float col[256];
  int n = blockIdx.x, k = threadIdx.x;
  if (k < K) col[k] = W[(size_t)k * N + n];
  __syncthreads();
  if (k < K / 2) Wt[(size_t)n * (K / 2) + k] = f2bf2(col[2 * k], col[2 * k + 1]);
}

// ---------------- MFMA bf16 GEMM: Cb[M][N](bf16) = (op(A) @ Bt^T) * dinv[row] ----------------
// A: f32 [M][K] (A_BF16=0) or packed-bf16 [M][K/2 uints] (A_BF16=1, optional relu)
// Bt: packed-bf16 [N][K/2 uints]  (= W^T)
// Block: 256 thr = 4 waves in WM x WN grid, each wave owns 64x64 output.
// LDS tiles swizzled: byte ^= (row&7)<<4 (bijective per 512B stripe, conflict-free b128 reads).
template<int BM, int BN, int WM, int A_BF16, int RELU>
__global__ __launch_bounds__(256) void mfma_gemm(const void* __restrict__ Av,
                                                 const uint* __restrict__ Bt,
                                                 const float* __restrict__ dinv,
                                                 ushort* __restrict__ Cb,
                                                 int M, int K, int N) {
  constexpr int BK = 32;
  constexpr int AU = BM * BK / 8;   // 16B units in A tile
  constexpr int BU = BN * BK / 8;
  __shared__ __align__(16) char smem[BM * BK * 2 + BN * BK * 2];
  char* Asm = smem;
  char* Bsm = smem + BM * BK * 2;

  const int tid  = threadIdx.x;
  const int wid  = tid >> 6;
  const int lane = tid & 63;
  const int wm   = wid % WM;
  const int wn   = wid / WM;
  const int blockRow = blockIdx.x * BM;
  const int l15  = lane & 15;
  const int lk   = lane >> 4;      // k-octet selector

  f32x4 acc[4][4];
#pragma unroll
  for (int i = 0; i < 4; ++i)
#pragma unroll
    for (int j = 0; j < 4; ++j) acc[i][j] = (f32x4){0.f, 0.f, 0.f, 0.f};

  for (int kk = 0; kk < K; kk += BK) {
    // ---- stage A tile [BM][BK] bf16, swizzled ----
#pragma unroll
    for (int i = 0; i < AU / 256; ++i) {
      int u = tid + i * 256;
      int row = u >> 2, oct = u & 3;
      int grow = blockRow + row;
      uint4 v = make_uint4(0, 0, 0, 0);
      if (grow < M) {
        if (A_BF16) {
          const uint* A = (const uint*)Av;
          v = *reinterpret_cast<const uint4*>(A + (size_t)grow * (K / 2) + (kk >> 1) + oct * 4);
          if (RELU) { v.x = relu2(v.x); v.y = relu2(v.y); v.z = relu2(v.z); v.w = relu2(v.w); }
        } else {
          const float* A = (const float*)Av;
          const float4* p = reinterpret_cast<const float4*>(A + (size_t)grow * K + kk + oct * 8);
          float4 f0 = p[0], f1 = p[1];
          v.x = f2bf2(f0.x, f0.y); v.y = f2bf2(f0.z, f0.w);
          v.z = f2bf2(f1.x, f1.y); v.w = f2bf2(f1.z, f1.w);
        }
      }
      int byte = (row * 64 + oct * 16) ^ ((row & 7) << 4);
      *reinterpret_cast<uint4*>(Asm + byte) = v;
    }
    // ---- stage B tile [BN][BK] bf16, swizzled ----
#pragma unroll
    for (int i = 0; i < BU / 256; ++i) {
      int u = tid + i * 256;
      int n = u >> 2, oct = u & 3;
      uint4 v = *reinterpret_cast<const uint4*>(Bt + (size_t)n * (K / 2) + (kk >> 1) + oct * 4);
      int byte = (n * 64 + oct * 16) ^ ((n & 7) << 4);
      *reinterpret_cast<uint4*>(Bsm + byte) = v;
    }
    __syncthreads();

    // ---- fragments + 16 MFMA ----
    bf16x8 af[4], bfr[4];
#pragma unroll
    for (int mt = 0; mt < 4; ++mt) {
      int row = wm * 64 + mt * 16 + l15;
      int byte = (row * 64 + (lk << 4)) ^ ((row & 7) << 4);
      af[mt] = __builtin_bit_cast(bf16x8, *reinterpret_cast<uint4*>(Asm + byte));
    }
#pragma unroll
    for (int nt = 0; nt < 4; ++nt) {
      int n = wn * 64 + nt * 16 + l15;
      int byte = (n * 64 + (lk << 4)) ^ ((n & 7) << 4);
      bfr[nt] = __builtin_bit_cast(bf16x8, *reinterpret_cast<uint4*>(Bsm + byte));
    }
#pragma unroll
    for (int mt = 0; mt < 4; ++mt)
#pragma unroll
      for (int nt = 0; nt < 4; ++nt)
        acc[mt][nt] = __builtin_amdgcn_mfma_f32_16x16x32_bf16(af[mt], bfr[nt], acc[mt][nt], 0, 0, 0);
    __syncthreads();
  }

  // ---- epilogue: C/D layout col=lane&15, row=(lane>>4)*4+j ----
#pragma unroll
  for (int mt = 0; mt < 4; ++mt) {
    int rbase = blockRow + wm * 64 + mt * 16 + lk * 4;
#pragma unroll
    for (int j = 0; j < 4; ++j) {
      int grow = rbase + j;
      if (grow < M) {
        float d = dinv[grow];
#pragma unroll
        for (int nt = 0; nt < 4; ++nt) {
          int gcol = wn * 64 + nt * 16 + l15;
          Cb[(size_t)grow * N + gcol] = f2bf(acc[mt][nt][j] * d);
        }
      }
    }
  }
}

// ---------------- CSR build ----------------
__global__ void deg_int(const int* __restrict__ dst, int* __restrict__ deg, int E) {
  int e = blockIdx.x * blockDim.x + threadIdx.x;
  if (e < E) atomicAdd(&deg[dst[e]], 1);
}

__global__ void dinv_from_deg(const int* __restrict__ deg, float* __restrict__ dinv, int N) {
  int n = blockIdx.x * blockDim.x + threadIdx.x;
  if (n < N) dinv[n] = rsqrtf((float)deg[n] + 1.0f);
}

__global__ void scan_block(const int* __restrict__ deg, int* __restrict__ row_off,
                           int* __restrict__ bsum, int N) {
  __shared__ int s[256];
  int t = threadIdx.x;
  int i = blockIdx.x * 256 + t;
  int v = (i < N) ? deg[i] : 0;
  s[t] = v;
  __syncthreads();
  for (int off = 1; off < 256; off <<= 1) {
    int add = (t >= off) ? s[t - off] : 0;
    __syncthreads();
    s[t] += add;
    __syncthreads();
  }
  if (i < N) row_off[i] = s[t] - v;
  if (t == 255) bsum[blockIdx.x] = s[255];
}

__global__ void scan_bsum(int* __restrict__ bsum, int NB) {
  __shared__ int s[512];
  int t = threadIdx.x;
  int v = (t < NB) ? bsum[t] : 0;
  s[t] = v;
  __syncthreads();
  for (int off = 1; off < 512; off <<= 1) {
    int add = (t >= off) ? s[t - off] : 0;
    __syncthreads();
    s[t] += add;
    __syncthreads();
  }
  if (t < NB) bsum[t] = s[t] - v;
}

__global__ void scan_final(int* __restrict__ row_off, int* __restrict__ cursor,
                           const int* __restrict__ bsum, int N, int E) {
  int i = blockIdx.x * 256 + threadIdx.x;
  if (i < N) {
    int r = row_off[i] + bsum[blockIdx.x];
    row_off[i] = r;
    cursor[i]  = r;
  }
  if (i == 0) row_off[N] = E;
}

// XCD-partitioned scatter: part p owns dst range [p*NN/8,(p+1)*NN/8)
__global__ __launch_bounds__(256) void scatter_csr_part(const int* __restrict__ src,
                                                        const int* __restrict__ dst,
                                                        int* __restrict__ cursor,
                                                        int* __restrict__ csr, int E) {
  int part  = blockIdx.x & (NPART - 1);
  int chunk = blockIdx.x / NPART;
  int per   = E / NCHUNK;
  int beg   = chunk * per, end = beg + per;
  int lo = part * (NN / NPART), hi = lo + (NN / NPART);
  for (int e = beg + threadIdx.x; e < end; e += 256) {
    int d = dst[e];
    if (d >= lo && d < hi) {
      int p = atomicAdd(&cursor[d], 1);
      csr[p] = src[e];
    }
  }
}

// ---------------- CSR gather-reduce from bf16 hs ----------------
// F=128: one wave per node; out packed bf16
__global__ __launch_bounds__(256) void agg_csr_f128(const uint* __restrict__ hs,
                                                    const float* __restrict__ dinv,
                                                    const float* __restrict__ bias,
                                                    const int* __restrict__ row_off,
                                                    const int* __restrict__ csr,
                                                    uint* __restrict__ outb, int N) {
  int node = blockIdx.x * 4 + (threadIdx.x >> 6);
  if (node >= N) return;
  int lane = threadIdx.x & 63;
  int beg = row_off[node], end = row_off[node + 1];
  float2 acc = bf2f(hs[(size_t)node * 64 + lane]);  // self term
  int j = beg;
  for (; j + 4 <= end; j += 4) {
    int s0 = csr[j], s1 = csr[j + 1], s2 = csr[j + 2], s3 = csr[j + 3];
    float2 v0 = bf2f(hs[(size_t)s0 * 64 + lane]);
    float2 v1 = bf2f(hs[(size_t)s1 * 64 + lane]);
    float2 v2 = bf2f(hs[(size_t)s2 * 64 + lane]);
    float2 v3 = bf2f(hs[(size_t)s3 * 64 + lane]);
    acc.x += (v0.x + v1.x) + (v2.x + v3.x);
    acc.y += (v0.y + v1.y) + (v2.y + v3.y);
  }
  for (; j < end; ++j) {
    float2 v = bf2f(hs[(size_t)csr[j] * 64 + lane]);
    acc.x += v.x; acc.y += v.y;
  }
  float d = dinv[node];
  float2 b = reinterpret_cast<const float2*>(bias)[lane];
  outb[(size_t)node * 64 + lane] = f2bf2(fmaf(acc.x, d, b.x), fmaf(acc.y, d, b.y));
}

// F=64: two nodes per wave; out f32 (feeds pool)
__global__ __launch_bounds__(256) void agg_csr_f64(const uint* __restrict__ hs,
                                                   const float* __restrict__ dinv,
                                                   const float* __restrict__ bias,
                                                   const int* __restrict__ row_off,
                                                   const int* __restrict__ csr,
                                                   float2* __restrict__ out, int N) {
  int node = blockIdx.x * 8 + (threadIdx.x >> 5);
  if (node >= N) return;
  int lane2 = threadIdx.x & 31;
  int beg = row_off[node], end = row_off[node + 1];
  float2 acc = bf2f(hs[(size_t)node * 32 + lane2]);
  int j = beg;
  for (; j + 4 <= end; j += 4) {
    int s0 = csr[j], s1 = csr[j + 1], s2 = csr[j + 2], s3 = csr[j + 3];
    float2 v0 = bf2f(hs[(size_t)s0 * 32 + lane2]);
    float2 v1 = bf2f(hs[(size_t)s1 * 32 + lane2]);
    float2 v2 = bf2f(hs[(size_t)s2 * 32 + lane2]);
    float2 v3 = bf2f(hs[(size_t)s3 * 32 + lane2]);
    acc.x += (v0.x + v1.x) + (v2.x + v3.x);
    acc.y += (v0.y + v1.y) + (v2.y + v3.y);
  }
  for (; j < end; ++j) {
    float2 v = bf2f(hs[(size_t)csr[j] * 32 + lane2]);
    acc.x += v.x; acc.y += v.y;
  }
  float d = dinv[node];
  float2 b = reinterpret_cast<const float2*>(bias)[lane2];
  float2 o;
  o.x = fmaf(acc.x, d, b.x);
  o.y = fmaf(acc.y, d, b.y);
  out[(size_t)node * 32 + lane2] = o;
}

// ---------------- per-graph mean pool (batch sorted) ----------------
__global__ __launch_bounds__(256) void pool_graph(const float* __restrict__ h,
                                                  const int* __restrict__ batch,
                                                  const float* __restrict__ scalars,
                                                  float* __restrict__ emb66, int N) {
  int g = blockIdx.x;
  int t = threadIdx.x;  // 256
  int col = t & 63, rr = t >> 6;
  __shared__ int range[2];
  __shared__ float part[4][64];
  if (t < 2) {
    int target = g + t;
    int lo = 0, hi = N;
    while (lo < hi) { int mid = (lo + hi) >> 1; if (batch[mid] < target) lo = mid + 1; else hi = mid; }
    range[t] = lo;
  }
  __syncthreads();
  int beg = range[0], end = range[1];
  float s = 0.f;
  for (int i = beg + rr; i < end; i += 4) s += h[(size_t)i * 64 + col];
  part[rr][col] = s;
  __syncthreads();
  if (rr == 0) {
    float tot = (part[0][col] + part[1][col]) + (part[2][col] + part[3][col]);
    emb66[g * 66 + col] = tot / fmaxf((float)(end - beg), 1.f);
  } else if (t >= 64 && t < 66) {
    emb66[g * 66 + t] = scalars[g * 2 + (t - 64)];
  }
}

// ---------------- per-graph MLP ----------------
__global__ __launch_bounds__(128) void graph_mlp(const float* __restrict__ emb66,
                                                 const float* __restrict__ W3,
                                                 const float* __restrict__ b3,
                                                 const float* __restrict__ W4,
                                                 const float* __restrict__ b4,
                                                 float* __restrict__ out) {
  int g = blockIdx.x;
  int t = threadIdx.x;  // 128
  __shared__ float comb[66];
  __shared__ float part[2];
  if (t < 66) comb[t] = emb66[g * 66 + t];
  __syncthreads();
  float h = b3[t];
#pragma unroll
  for (int k = 0; k < 66; ++k) h += comb[k] * W3[k * 128 + t];
  h = fmaxf(h, 0.f);
  float p = h * W4[t];
#pragma unroll
  for (int off = 32; off > 0; off >>= 1) p += __shfl_down(p, off);
  if ((t & 63) == 0) part[t >> 6] = p;
  __syncthreads();
  if (t == 0) {
    float s = part[0] + part[1] + b4[0];
    out[g] = 1.f / (1.f + expf(-s));
  }
}

extern "C" void kernel_launch(void* const* d_in, const int* in_sizes, int n_in,
                              void* d_out, int out_size, void* d_ws, size_t ws_size,
                              hipStream_t stream) {
  const float* x       = (const float*)d_in[0];
  const int*   ei      = (const int*)d_in[1];
  const int*   src     = ei;
  const int*   dstp    = ei + NE;
  const int*   batch   = (const int*)d_in[2];
  const float* scalars = (const float*)d_in[3];
  const float* W1 = (const float*)d_in[4];  const float* b1 = (const float*)d_in[5];
  const float* W2 = (const float*)d_in[6];  const float* b2 = (const float*)d_in[7];
  const float* W3 = (const float*)d_in[8];  const float* b3 = (const float*)d_in[9];
  const float* W4 = (const float*)d_in[10]; const float* b4 = (const float*)d_in[11];
  float* out = (float*)d_out;

  // workspace layout (32-bit words)
  uint*  ws      = (uint*)d_ws;
  uint*  hsb     = ws;                     // [100000,64]u conv1 hs bf16; reused as hs2b [100000,32]u
  uint*  agg1b   = ws + 6400000;           // [100000,64]u conv1 agg bf16; reused as agg2 f32 [100000,64]
  float* dinv    = (float*)(ws + 12800000);// [100000]
  int*   deg     = (int*)(dinv + NN);      // [100000]
  int*   row_off = deg + NN;               // [100001]
  int*   cursor  = row_off + NN + 1;       // [100000]
  int*   bsum    = cursor + NN;            // [512]
  int*   csr     = bsum + 512;             // [1600000]
  uint*  w1t     = (uint*)(csr + NE);      // [128,128]u  (W1^T bf16)
  uint*  w2t     = w1t + 128 * 128;        // [64,64]u    (W2^T bf16)
  float* emb66   = (float*)(w2t + 64 * 64);// [512,66]

  hipMemsetAsync(deg, 0, (size_t)NN * sizeof(int), stream);

  // weight transposes (bf16 pack)
  transpose_w<<<128, 256, 0, stream>>>(W1, w1t, 256, 128);
  transpose_w<<<64, 128, 0, stream>>>(W2, w2t, 128, 64);

  // CSR build + norms
  deg_int<<<(NE + 255) / 256, 256, 0, stream>>>(dstp, deg, NE);
  dinv_from_deg<<<NB_SCAN, 256, 0, stream>>>(deg, dinv, NN);
  scan_block<<<NB_SCAN, 256, 0, stream>>>(deg, row_off, bsum, NN);
  scan_bsum<<<1, 512, 0, stream>>>(bsum, NB_SCAN);
  scan_final<<<NB_SCAN, 256, 0, stream>>>(row_off, cursor, bsum, NN, NE);
  scatter_csr_part<<<NPART * NCHUNK, 256, 0, stream>>>(src, dstp, cursor, csr, NE);

  // conv1: hsb = bf16((x @ W1) * dinv) ; agg1b = bf16(dinv*(gather+self) + b1)
  mfma_gemm<128, 128, 2, 0, 0><<<(NN + 127) / 128, 256, 0, stream>>>(
      x, w1t, dinv, (ushort*)hsb, NN, 256, 128);
  agg_csr_f128<<<(NN + 3) / 4, 256, 0, stream>>>(hsb, dinv, b1, row_off, csr, agg1b, NN);

  // conv2: hs2b = bf16((relu(agg1b) @ W2) * dinv) ; agg2 = dinv*(gather+self) + b2 (f32)
  mfma_gemm<256, 64, 4, 1, 1><<<(NN + 255) / 256, 256, 0, stream>>>(
      agg1b, w2t, dinv, (ushort*)hsb, NN, 128, 64);
  agg_csr_f64<<<(NN + 7) / 8, 256, 0, stream>>>(hsb, dinv, b2, row_off, csr,
                                                (float2*)agg1b, NN);

  // pool + MLP
  pool_graph<<<NG, 256, 0, stream>>>((const float*)agg1b, batch, scalars, emb66, NN);
  graph_mlp<<<NG, 128, 0, stream>>>(emb66, W3, b3, W4, b4, out);
}

// Round 5
// 267.505 us; speedup vs baseline: 16.7387x; 1.3246x over previous
//
#include <hip/hip_runtime.h>

#define NN 100000
#define NE 1600000
#define NG 512
#define NPARTS 500    // dst partitions
#define PW 200        // partition width (500*200 = 100000)
#define NCHUNKS 128   // edge chunks
#define CE 12500      // edges per chunk (128*12500 = 1.6M)
#define NCNT (NPARTS * NCHUNKS)

typedef unsigned int uint;
typedef unsigned short ushort;
typedef __bf16 bf16x8 __attribute__((ext_vector_type(8)));
typedef float f32x4 __attribute__((ext_vector_type(4)));

// ---- bf16 pack helpers (round-to-nearest-even) ----
__device__ inline uint f2bf2(float a, float b) {
  uint ua = __float_as_uint(a), ub = __float_as_uint(b);
  ua += 0x7fff + ((ua >> 16) & 1);
  ub += 0x7fff + ((ub >> 16) & 1);
  return (ua >> 16) | (ub & 0xffff0000u);
}
__device__ inline ushort f2bf(float f) {
  uint u = __float_as_uint(f);
  u += 0x7fff + ((u >> 16) & 1);
  return (ushort)(u >> 16);
}
__device__ inline float2 bf2f(uint v) {
  float2 r;
  r.x = __uint_as_float(v << 16);
  r.y = __uint_as_float(v & 0xffff0000u);
  return r;
}
__device__ inline uint relu2(uint u) {
  uint lo = (u & 0x8000u) ? 0u : (u & 0xFFFFu);
  uint hi = (u & 0x80000000u) ? 0u : (u & 0xFFFF0000u);
  return lo | hi;
}

// ---------------- weight transpose + bf16 pack: Wt[n][k] = bf16(W[k][n]) ----------------
__global__ void transpose_w(const float* __restrict__ W, uint* __restrict__ Wt, int K, int N) {
  __shared__ float col[256];
  int n = blockIdx.x, k = threadIdx.x;
  if (k < K) col[k] = W[(size_t)k * N + n];
  __syncthreads();
  if (k < K / 2) Wt[(size_t)n * (K / 2) + k] = f2bf2(col[2 * k], col[2 * k + 1]);
}

// ---------------- CSR build: counting sort, all RMW in LDS ----------------
// Pass A: cnt[part][chunk] = #edges in chunk with dst in partition
__global__ __launch_bounds__(256) void bucket_count(const int* __restrict__ dst,
                                                    int* __restrict__ cnt) {
  __shared__ int h[NPARTS];
  int t = threadIdx.x, c = blockIdx.x;
  for (int i = t; i < NPARTS; i += 256) h[i] = 0;
  __syncthreads();
  int beg = c * CE;
  for (int j = t; j < CE; j += 256) atomicAdd(&h[dst[beg + j] / PW], 1);
  __syncthreads();
  for (int i = t; i < NPARTS; i += 256) cnt[i * NCHUNKS + c] = h[i];
}

// Generic scan (exclusive), 3 kernels; in-place safe (reads before writes per block)
__global__ void scan1(const int* __restrict__ in, int* __restrict__ out,
                      int* __restrict__ bsum, int n) {
  __shared__ int s[256];
  int t = threadIdx.x;
  int i = blockIdx.x * 256 + t;
  int v = (i < n) ? in[i] : 0;
  s[t] = v;
  __syncthreads();
  for (int off = 1; off < 256; off <<= 1) {
    int add = (t >= off) ? s[t - off] : 0;
    __syncthreads();
    s[t] += add;
    __syncthreads();
  }
  if (i < n) out[i] = s[t] - v;
  if (t == 255) bsum[blockIdx.x] = s[255];
}

__global__ void scan2(int* __restrict__ bsum, int nb) {
  __shared__ int s[512];
  int t = threadIdx.x;
  int v = (t < nb) ? bsum[t] : 0;
  s[t] = v;
  __syncthreads();
  for (int off = 1; off < 512; off <<= 1) {
    int add = (t >= off) ? s[t - off] : 0;
    __syncthreads();
    s[t] += add;
    __syncthreads();
  }
  if (t < nb) bsum[t] = s[t] - v;
}

__global__ void scan3(int* __restrict__ out, const int* __restrict__ bsum, int n) {
  int i = blockIdx.x * 256 + threadIdx.x;
  if (i < n) out[i] += bsum[blockIdx.x];
}

// Pass C: bucket edges -> pk[pos] = src | (dst_local << 17), slices disjoint per (chunk,part)
__global__ __launch_bounds__(256) void bucket_scatter(const int* __restrict__ src,
                                                      const int* __restrict__ dst,
                                                      const int* __restrict__ off,
                                                      uint* __restrict__ pk) {
  __shared__ int cur[NPARTS];
  int t = threadIdx.x, c = blockIdx.x;
  for (int i = t; i < NPARTS; i += 256) cur[i] = off[i * NCHUNKS + c];
  __syncthreads();
  int beg = c * CE;
  for (int j = t; j < CE; j += 256) {
    int d = dst[beg + j];
    int p = d / PW;
    int pos = atomicAdd(&cur[p], 1);
    pk[pos] = (uint)src[beg + j] | ((uint)(d - p * PW) << 17);
  }
}

// Pass D: per-partition local CSR: row_off, dinv, csr (contiguous span)
__global__ __launch_bounds__(256) void csr_finalize(const uint* __restrict__ pk,
                                                    const int* __restrict__ off,
                                                    int* __restrict__ row_off,
                                                    float* __restrict__ dinv,
                                                    int* __restrict__ csr) {
  __shared__ int hist[PW];
  __shared__ int cur[PW];
  __shared__ int s[256];
  int p = blockIdx.x, t = threadIdx.x;
  int base = off[p * NCHUNKS];
  int endp = (p == NPARTS - 1) ? NE : off[(p + 1) * NCHUNKS];
  if (t < PW) hist[t] = 0;
  __syncthreads();
  for (int j = base + t; j < endp; j += 256) atomicAdd(&hist[pk[j] >> 17], 1);
  __syncthreads();
  int v = (t < PW) ? hist[t] : 0;
  s[t] = v;
  __syncthreads();
  for (int o = 1; o < 256; o <<= 1) {
    int add = (t >= o) ? s[t - o] : 0;
    __syncthreads();
    s[t] += add;
    __syncthreads();
  }
  if (t < PW) {
    int excl = base + (s[t] - v);
    int node = p * PW + t;
    row_off[node] = excl;
    dinv[node]    = rsqrtf((float)v + 1.0f);
    cur[t] = excl;
  }
  if (p == NPARTS - 1 && t == 0) row_off[NN] = NE;
  __syncthreads();
  for (int j = base + t; j < endp; j += 256) {
    uint e = pk[j];
    int pos = atomicAdd(&cur[e >> 17], 1);
    csr[pos] = (int)(e & 0x1FFFFu);
  }
}

// ---------------- MFMA bf16 GEMM (unchanged from r4) ----------------
template<int BM, int BN, int WM, int A_BF16, int RELU>
__global__ __launch_bounds__(256) void mfma_gemm(const void* __restrict__ Av,
                                                 const uint* __restrict__ Bt,
                                                 const float* __restrict__ dinv,
                                                 ushort* __restrict__ Cb,
                                                 int M, int K, int N) {
  constexpr int BK = 32;
  constexpr int AU = BM * BK / 8;
  constexpr int BU = BN * BK / 8;
  __shared__ __align__(16) char smem[BM * BK * 2 + BN * BK * 2];
  char* Asm = smem;
  char* Bsm = smem + BM * BK * 2;

  const int tid  = threadIdx.x;
  const int wid  = tid >> 6;
  const int lane = tid & 63;
  const int wm   = wid % WM;
  const int wn   = wid / WM;
  const int blockRow = blockIdx.x * BM;
  const int l15  = lane & 15;
  const int lk   = lane >> 4;

  f32x4 acc[4][4];
#pragma unroll
  for (int i = 0; i < 4; ++i)
#pragma unroll
    for (int j = 0; j < 4; ++j) acc[i][j] = (f32x4){0.f, 0.f, 0.f, 0.f};

  for (int kk = 0; kk < K; kk += BK) {
#pragma unroll
    for (int i = 0; i < AU / 256; ++i) {
      int u = tid + i * 256;
      int row = u >> 2, oct = u & 3;
      int grow = blockRow + row;
      uint4 v = make_uint4(0, 0, 0, 0);
      if (grow < M) {
        if (A_BF16) {
          const uint* A = (const uint*)Av;
          v = *reinterpret_cast<const uint4*>(A + (size_t)grow * (K / 2) + (kk >> 1) + oct * 4);
          if (RELU) { v.x = relu2(v.x); v.y = relu2(v.y); v.z = relu2(v.z); v.w = relu2(v.w); }
        } else {
          const float* A = (const float*)Av;
          const float4* ptr = reinterpret_cast<const float4*>(A + (size_t)grow * K + kk + oct * 8);
          float4 f0 = ptr[0], f1 = ptr[1];
          v.x = f2bf2(f0.x, f0.y); v.y = f2bf2(f0.z, f0.w);
          v.z = f2bf2(f1.x, f1.y); v.w = f2bf2(f1.z, f1.w);
        }
      }
      int byte = (row * 64 + oct * 16) ^ ((row & 7) << 4);
      *reinterpret_cast<uint4*>(Asm + byte) = v;
    }
#pragma unroll
    for (int i = 0; i < BU / 256; ++i) {
      int u = tid + i * 256;
      int n = u >> 2, oct = u & 3;
      uint4 v = *reinterpret_cast<const uint4*>(Bt + (size_t)n * (K / 2) + (kk >> 1) + oct * 4);
      int byte = (n * 64 + oct * 16) ^ ((n & 7) << 4);
      *reinterpret_cast<uint4*>(Bsm + byte) = v;
    }
    __syncthreads();

    bf16x8 af[4], bfr[4];
#pragma unroll
    for (int mt = 0; mt < 4; ++mt) {
      int row = wm * 64 + mt * 16 + l15;
      int byte = (row * 64 + (lk << 4)) ^ ((row & 7) << 4);
      af[mt] = __builtin_bit_cast(bf16x8, *reinterpret_cast<uint4*>(Asm + byte));
    }
#pragma unroll
    for (int nt = 0; nt < 4; ++nt) {
      int n = wn * 64 + nt * 16 + l15;
      int byte = (n * 64 + (lk << 4)) ^ ((n & 7) << 4);
      bfr[nt] = __builtin_bit_cast(bf16x8, *reinterpret_cast<uint4*>(Bsm + byte));
    }
#pragma unroll
    for (int mt = 0; mt < 4; ++mt)
#pragma unroll
      for (int nt = 0; nt < 4; ++nt)
        acc[mt][nt] = __builtin_amdgcn_mfma_f32_16x16x32_bf16(af[mt], bfr[nt], acc[mt][nt], 0, 0, 0);
    __syncthreads();
  }

#pragma unroll
  for (int mt = 0; mt < 4; ++mt) {
    int rbase = blockRow + wm * 64 + mt * 16 + lk * 4;
#pragma unroll
    for (int j = 0; j < 4; ++j) {
      int grow = rbase + j;
      if (grow < M) {
        float d = dinv[grow];
#pragma unroll
        for (int nt = 0; nt < 4; ++nt) {
          int gcol = wn * 64 + nt * 16 + l15;
          Cb[(size_t)grow * N + gcol] = f2bf(acc[mt][nt][j] * d);
        }
      }
    }
  }
}

// ---------------- CSR gather-reduce from bf16 hs ----------------
__global__ __launch_bounds__(256) void agg_csr_f128(const uint* __restrict__ hs,
                                                    const float* __restrict__ dinv,
                                                    const float* __restrict__ bias,
                                                    const int* __restrict__ row_off,
                                                    const int* __restrict__ csr,
                                                    uint* __restrict__ outb, int N) {
  int node = blockIdx.x * 4 + (threadIdx.x >> 6);
  if (node >= N) return;
  int lane = threadIdx.x & 63;
  int beg = row_off[node], end = row_off[node + 1];
  float2 acc = bf2f(hs[(size_t)node * 64 + lane]);
  int j = beg;
  for (; j + 4 <= end; j += 4) {
    int s0 = csr[j], s1 = csr[j + 1], s2 = csr[j + 2], s3 = csr[j + 3];
    float2 v0 = bf2f(hs[(size_t)s0 * 64 + lane]);
    float2 v1 = bf2f(hs[(size_t)s1 * 64 + lane]);
    float2 v2 = bf2f(hs[(size_t)s2 * 64 + lane]);
    float2 v3 = bf2f(hs[(size_t)s3 * 64 + lane]);
    acc.x += (v0.x + v1.x) + (v2.x + v3.x);
    acc.y += (v0.y + v1.y) + (v2.y + v3.y);
  }
  for (; j < end; ++j) {
    float2 v = bf2f(hs[(size_t)csr[j] * 64 + lane]);
    acc.x += v.x; acc.y += v.y;
  }
  float d = dinv[node];
  float2 b = reinterpret_cast<const float2*>(bias)[lane];
  outb[(size_t)node * 64 + lane] = f2bf2(fmaf(acc.x, d, b.x), fmaf(acc.y, d, b.y));
}

__global__ __launch_bounds__(256) void agg_csr_f64(const uint* __restrict__ hs,
                                                   const float* __restrict__ dinv,
                                                   const float* __restrict__ bias,
                                                   const int* __restrict__ row_off,
                                                   const int* __restrict__ csr,
                                                   float2* __restrict__ out, int N) {
  int node = blockIdx.x * 8 + (threadIdx.x >> 5);
  if (node >= N) return;
  int lane2 = threadIdx.x & 31;
  int beg = row_off[node], end = row_off[node + 1];
  float2 acc = bf2f(hs[(size_t)node * 32 + lane2]);
  int j = beg;
  for (; j + 4 <= end; j += 4) {
    int s0 = csr[j], s1 = csr[j + 1], s2 = csr[j + 2], s3 = csr[j + 3];
    float2 v0 = bf2f(hs[(size_t)s0 * 32 + lane2]);
    float2 v1 = bf2f(hs[(size_t)s1 * 32 + lane2]);
    float2 v2 = bf2f(hs[(size_t)s2 * 32 + lane2]);
    float2 v3 = bf2f(hs[(size_t)s3 * 32 + lane2]);
    acc.x += (v0.x + v1.x) + (v2.x + v3.x);
    acc.y += (v0.y + v1.y) + (v2.y + v3.y);
  }
  for (; j < end; ++j) {
    float2 v = bf2f(hs[(size_t)csr[j] * 32 + lane2]);
    acc.x += v.x; acc.y += v.y;
  }
  float d = dinv[node];
  float2 b = reinterpret_cast<const float2*>(bias)[lane2];
  float2 o;
  o.x = fmaf(acc.x, d, b.x);
  o.y = fmaf(acc.y, d, b.y);
  out[(size_t)node * 32 + lane2] = o;
}

// ---------------- per-graph mean pool (batch sorted) ----------------
__global__ __launch_bounds__(256) void pool_graph(const float* __restrict__ h,
                                                  const int* __restrict__ batch,
                                                  const float* __restrict__ scalars,
                                                  float* __restrict__ emb66, int N) {
  int g = blockIdx.x;
  int t = threadIdx.x;
  int col = t & 63, rr = t >> 6;
  __shared__ int range[2];
  __shared__ float part[4][64];
  if (t < 2) {
    int target = g + t;
    int lo = 0, hi = N;
    while (lo < hi) { int mid = (lo + hi) >> 1; if (batch[mid] < target) lo = mid + 1; else hi = mid; }
    range[t] = lo;
  }
  __syncthreads();
  int beg = range[0], end = range[1];
  float s = 0.f;
  for (int i = beg + rr; i < end; i += 4) s += h[(size_t)i * 64 + col];
  part[rr][col] = s;
  __syncthreads();
  if (rr == 0) {
    float tot = (part[0][col] + part[1][col]) + (part[2][col] + part[3][col]);
    emb66[g * 66 + col] = tot / fmaxf((float)(end - beg), 1.f);
  } else if (t >= 64 && t < 66) {
    emb66[g * 66 + t] = scalars[g * 2 + (t - 64)];
  }
}

// ---------------- per-graph MLP ----------------
__global__ __launch_bounds__(128) void graph_mlp(const float* __restrict__ emb66,
                                                 const float* __restrict__ W3,
                                                 const float* __restrict__ b3,
                                                 const float* __restrict__ W4,
                                                 const float* __restrict__ b4,
                                                 float* __restrict__ out) {
  int g = blockIdx.x;
  int t = threadIdx.x;
  __shared__ float comb[66];
  __shared__ float part[2];
  if (t < 66) comb[t] = emb66[g * 66 + t];
  __syncthreads();
  float h = b3[t];
#pragma unroll
  for (int k = 0; k < 66; ++k) h += comb[k] * W3[k * 128 + t];
  h = fmaxf(h, 0.f);
  float p = h * W4[t];
#pragma unroll
  for (int off = 32; off > 0; off >>= 1) p += __shfl_down(p, off);
  if ((t & 63) == 0) part[t >> 6] = p;
  __syncthreads();
  if (t == 0) {
    float s = part[0] + part[1] + b4[0];
    out[g] = 1.f / (1.f + expf(-s));
  }
}

extern "C" void kernel_launch(void* const* d_in, const int* in_sizes, int n_in,
                              void* d_out, int out_size, void* d_ws, size_t ws_size,
                              hipStream_t stream) {
  const float* x       = (const float*)d_in[0];
  const int*   ei      = (const int*)d_in[1];
  const int*   src     = ei;
  const int*   dstp    = ei + NE;
  const int*   batch   = (const int*)d_in[2];
  const float* scalars = (const float*)d_in[3];
  const float* W1 = (const float*)d_in[4];  const float* b1 = (const float*)d_in[5];
  const float* W2 = (const float*)d_in[6];  const float* b2 = (const float*)d_in[7];
  const float* W3 = (const float*)d_in[8];  const float* b3 = (const float*)d_in[9];
  const float* W4 = (const float*)d_in[10]; const float* b4 = (const float*)d_in[11];
  float* out = (float*)d_out;

  // workspace layout (32-bit words)
  uint*  ws      = (uint*)d_ws;
  uint*  hsb     = ws;                      // [100000,64]u bf16 hs; reused [100000,32]u
  uint*  agg1b   = ws + 6400000;            // [100000,64]u bf16 agg1; reused agg2 f32 [100000,64]
  float* dinv    = (float*)(ws + 12800000); // [100000]
  int*   row_off = (int*)(dinv + NN);       // [100001]
  int*   csr     = row_off + NN + 1;        // [1600000]
  uint*  pk      = (uint*)(csr + NE);       // [1600000] bucketed packed edges
  int*   cnt     = (int*)(pk + NE);         // [64000] counts -> offsets (in-place scan)
  int*   bsum    = cnt + NCNT;              // [512]
  uint*  w1t     = (uint*)(bsum + 512);     // [128*128]
  uint*  w2t     = w1t + 128 * 128;         // [64*64]
  float* emb66   = (float*)(w2t + 64 * 64); // [512,66]

  // CSR build (no global atomics)
  bucket_count<<<NCHUNKS, 256, 0, stream>>>(dstp, cnt);
  scan1<<<(NCNT + 255) / 256, 256, 0, stream>>>(cnt, cnt, bsum, NCNT);
  scan2<<<1, 512, 0, stream>>>(bsum, (NCNT + 255) / 256);
  scan3<<<(NCNT + 255) / 256, 256, 0, stream>>>(cnt, bsum, NCNT);
  bucket_scatter<<<NCHUNKS, 256, 0, stream>>>(src, dstp, cnt, pk);
  csr_finalize<<<NPARTS, 256, 0, stream>>>(pk, cnt, row_off, dinv, csr);

  // weight transposes (bf16 pack)
  transpose_w<<<128, 256, 0, stream>>>(W1, w1t, 256, 128);
  transpose_w<<<64, 128, 0, stream>>>(W2, w2t, 128, 64);

  // conv1: hsb = bf16((x @ W1) * dinv) ; agg1b = bf16(dinv*(gather+self) + b1)
  mfma_gemm<128, 128, 2, 0, 0><<<(NN + 127) / 128, 256, 0, stream>>>(
      x, w1t, dinv, (ushort*)hsb, NN, 256, 128);
  agg_csr_f128<<<(NN + 3) / 4, 256, 0, stream>>>(hsb, dinv, b1, row_off, csr, agg1b, NN);

  // conv2: hsb = bf16((relu(agg1b) @ W2) * dinv) ; agg2 = dinv*(gather+self) + b2 (f32)
  mfma_gemm<256, 64, 4, 1, 1><<<(NN + 255) / 256, 256, 0, stream>>>(
      agg1b, w2t, dinv, (ushort*)hsb, NN, 128, 64);
  agg_csr_f64<<<(NN + 7) / 8, 256, 0, stream>>>(hsb, dinv, b2, row_off, csr,
                                                (float2*)agg1b, NN);

  // pool + MLP
  pool_graph<<<NG, 256, 0, stream>>>((const float*)agg1b, batch, scalars, emb66, NN);
  graph_mlp<<<NG, 128, 0, stream>>>(emb66, W3, b3, W4, b4, out);
}